// Round 1
// baseline (9144.568 us; speedup 1.0000x reference)
//
#include <hip/hip_runtime.h>
#include <stdint.h>

// ---------------------------------------------------------------------------
// GCN forward on MI355X.
//   mod = relu(adj @ sw + sb);  a = mod + I;  dinv = rsqrt(rowsum(a))
//   adjf = dinv_i * a * dinv_j
//   h0 = relu(adjf @ (x@W0) + b0); h1 = relu(adjf @ (h0@W1) + b1)
//   h2 = adjf @ (h1@W2) + b2;  out = log_softmax(h2, axis=1)
//
// All GEMMs run as split-bf16 (hi/lo decomposition, 3 MFMA products,
// fp32 accumulate) => ~fp32 accuracy at MFMA rates. NPROD=1 flips to plain
// bf16 (3x faster big GEMM) once validation tolerance is known.
// Workspace layout (needs ~530 MB):
//   swT 256MB | mod/adjf 256MB | xwT 8MB | h 8MB | h2 1.25MB | dinv | W*T
// ---------------------------------------------------------------------------

#define NPROD 3

typedef __attribute__((ext_vector_type(8))) short short8;   // 8 bf16 = 4 VGPR
typedef __attribute__((ext_vector_type(4))) float f32x4;

#define OFF_SWT  ((size_t)0)
#define OFF_MOD  ((size_t)268435456)
#define OFF_XWT  ((size_t)536870912)
#define OFF_H    (OFF_XWT + 8388608)
#define OFF_H2   (OFF_H + 8388608)
#define OFF_DINV (OFF_H2 + 1310720)
#define OFF_W0T  (OFF_DINV + 32768)
#define OFF_W1T  (OFF_W0T + 524288)
#define OFF_W2T  (OFF_W1T + 262144)

// fp32 -> (bf16 hi RNE, bf16 lo trunc) for two values, packed k/k+1 into u32.
__device__ __forceinline__ void split2(float x0, float x1, uint32_t& hi, uint32_t& lo) {
  uint32_t u0 = __float_as_uint(x0), u1 = __float_as_uint(x1);
  uint32_t r0 = (u0 + 0x7fffu + ((u0 >> 16) & 1u)) & 0xffff0000u;
  uint32_t r1 = (u1 + 0x7fffu + ((u1 >> 16) & 1u)) & 0xffff0000u;
  float f0 = x0 - __uint_as_float(r0);
  float f1 = x1 - __uint_as_float(r1);
  hi = (r0 >> 16) | r1;
  lo = (__float_as_uint(f0) >> 16) | (__float_as_uint(f1) & 0xffff0000u);
}

// LDS tile layout: [row][hl][k] bf16, row stride 128 B (8 chunks of 16 B),
// chunk-XOR swizzled by row&7 so frag ds_read_b128 is 2-way (free) and
// column reads spread across all banks.
__device__ __forceinline__ int lds_off(int row, int hl, int k) {
  int chunk = (hl << 2) | (k >> 3);
  return (row << 7) + ((chunk ^ (row & 7)) << 4) + ((k & 7) << 1);
}

// C[m][n] = act( sum_k A[m][k]*Bt[n][k] + bias[n] )
// A: [M][K] fp32 row-major.  Bt: [N][K] fp32 (i.e. B pre-transposed).
// 4 waves in 2x2, wave tile (BM/2)x(BN/2), BK=32, 16x16x32 bf16 MFMA.
template<int BM, int BN, int MAP, bool RELU, bool BIAS>
__global__ __launch_bounds__(256, 2)
void gemm_split(const float* __restrict__ A, const float* __restrict__ Bt,
                const float* __restrict__ bias, float* __restrict__ C,
                int M, int N, int K) {
  constexpr int WM = BM / 2, WN = BN / 2;
  constexpr int MF = WM / 16, NF = WN / 16;
  constexpr int PA = BM / 32, PB = BN / 32;
  __shared__ char smem[(BM + BN) * 128];
  char* smA = smem;
  char* smB = smem + BM * 128;

  const int tid  = threadIdx.x;
  const int lane = tid & 63;
  const int wid  = tid >> 6;
  const int l16  = lane & 15;
  const int lk8  = (lane >> 4) << 3;

  const int nbn = (N + BN - 1) / BN;
  int bm_i, bn_i;
  if (MAP == 1) {            // grouped: 8 row-tiles share each B column panel
    const int per = 8 * nbn;
    int g = blockIdx.x / per, r = blockIdx.x % per;
    bm_i = g * 8 + (r & 7);
    bn_i = r >> 3;
  } else {
    bm_i = blockIdx.x / nbn;
    bn_i = blockIdx.x % nbn;
  }
  const int bm = bm_i * BM, bn = bn_i * BN;

  // staging mapping: 32 rows x 32 k per pass, 4 fp32 per thread
  const int tr = tid >> 3;
  const int tc = (tid & 7) << 2;

  const float* aptr[PA]; bool aok[PA]; int aoff[PA];
#pragma unroll
  for (int p = 0; p < PA; ++p) {
    int row = p * 32 + tr;
    int gr  = bm + row;
    aok[p]  = gr < M;
    aptr[p] = A + (size_t)gr * K + tc;
    aoff[p] = lds_off(row, 0, tc);
  }
  const float* bptr[PB]; bool bok[PB]; int boff[PB];
#pragma unroll
  for (int p = 0; p < PB; ++p) {
    int row = p * 32 + tr;
    int gc  = bn + row;
    bok[p]  = gc < N;
    bptr[p] = Bt + (size_t)gc * K + tc;
    boff[p] = lds_off(row, 0, tc);
  }

  int offFA[MF], offFB[NF];
#pragma unroll
  for (int m = 0; m < MF; ++m)
    offFA[m] = lds_off((wid >> 1) * WM + m * 16 + l16, 0, lk8);
#pragma unroll
  for (int n = 0; n < NF; ++n)
    offFB[n] = lds_off((wid & 1) * WN + n * 16 + l16, 0, lk8);

  f32x4 acc[MF][NF] = {};
  const int NT = K >> 5;              // K % 64 == 0 for all call sites

  float4 cA[PA], cB[PB], nA[PA], nB[PB];

  auto LOADT = [&](float4* va, float4* vb, int kt) {
    const size_t ko = (size_t)kt << 5;
#pragma unroll
    for (int p = 0; p < PA; ++p) {
      float4 v = make_float4(0.f, 0.f, 0.f, 0.f);
      if (aok[p]) v = *(const float4*)(aptr[p] + ko);
      va[p] = v;
    }
#pragma unroll
    for (int p = 0; p < PB; ++p) {
      float4 v = make_float4(0.f, 0.f, 0.f, 0.f);
      if (bok[p]) v = *(const float4*)(bptr[p] + ko);
      vb[p] = v;
    }
  };

  auto STAGE = [&](const float4* va, const float4* vb) {
#pragma unroll
    for (int p = 0; p < PA; ++p) {
      uint32_t h0, l0, h1, l1;
      split2(va[p].x, va[p].y, h0, l0);
      split2(va[p].z, va[p].w, h1, l1);
      *(uint2*)(smA + aoff[p])        = make_uint2(h0, h1);
      *(uint2*)(smA + (aoff[p] ^ 64)) = make_uint2(l0, l1);
    }
#pragma unroll
    for (int p = 0; p < PB; ++p) {
      uint32_t h0, l0, h1, l1;
      split2(vb[p].x, vb[p].y, h0, l0);
      split2(vb[p].z, vb[p].w, h1, l1);
      *(uint2*)(smB + boff[p])        = make_uint2(h0, h1);
      *(uint2*)(smB + (boff[p] ^ 64)) = make_uint2(l0, l1);
    }
  };

  auto COMPUTE = [&]() {
    short8 aH[MF], aL[MF];
#pragma unroll
    for (int m = 0; m < MF; ++m) {
      aH[m] = *(const short8*)(smA + offFA[m]);
      aL[m] = *(const short8*)(smA + (offFA[m] ^ 64));
    }
#pragma unroll
    for (int n = 0; n < NF; ++n) {
      short8 bH = *(const short8*)(smB + offFB[n]);
      short8 bL = *(const short8*)(smB + (offFB[n] ^ 64));
#pragma unroll
      for (int m = 0; m < MF; ++m) {
        acc[m][n] = __builtin_amdgcn_mfma_f32_16x16x32_bf16(aH[m], bH, acc[m][n], 0, 0, 0);
#if NPROD >= 3
        acc[m][n] = __builtin_amdgcn_mfma_f32_16x16x32_bf16(aH[m], bL, acc[m][n], 0, 0, 0);
        acc[m][n] = __builtin_amdgcn_mfma_f32_16x16x32_bf16(aL[m], bH, acc[m][n], 0, 0, 0);
#endif
      }
    }
  };

  LOADT(cA, cB, 0);
  for (int kt = 0; kt < NT; kt += 2) {
    STAGE(cA, cB);
    __syncthreads();
    LOADT(nA, nB, kt + 1);       // issue early: HBM latency hides under MFMA
    COMPUTE();
    __syncthreads();
    STAGE(nA, nB);
    __syncthreads();
    if (kt + 2 < NT) LOADT(cA, cB, kt + 2);
    COMPUTE();
    __syncthreads();
  }

  const int wm = (wid >> 1) * WM, wn = (wid & 1) * WN;
#pragma unroll
  for (int n = 0; n < NF; ++n) {
    int gn = bn + wn + n * 16 + l16;
    float bv = 0.f;
    if (BIAS && gn < N) bv = bias[gn];
#pragma unroll
    for (int m = 0; m < MF; ++m) {
      int gm0 = bm + wm + m * 16 + ((lane >> 4) << 2);
#pragma unroll
      for (int r = 0; r < 4; ++r) {
        int gm = gm0 + r;
        if (gm < M && gn < N) {
          float v = acc[m][n][r] + bv;
          if (RELU) v = fmaxf(v, 0.f);
          C[(size_t)gm * N + gn] = v;
        }
      }
    }
  }
}

// out[c][r] = in[r][c], 64x64 LDS tiles, both sides coalesced.
__global__ void transpose_f32(const float* __restrict__ in, float* __restrict__ out,
                              int R, int C) {
  __shared__ float tile[64][65];
  int bx = blockIdx.x << 6;
  int by = blockIdx.y << 6;
  int x  = threadIdx.x;
  int ys = threadIdx.y;
#pragma unroll
  for (int i = 0; i < 64; i += 4) {
    int r = by + ys + i, c = bx + x;
    float v = 0.f;
    if (r < R && c < C) v = in[(size_t)r * C + c];
    tile[ys + i][x] = v;
  }
  __syncthreads();
#pragma unroll
  for (int i = 0; i < 64; i += 4) {
    int orow = bx + ys + i, oc = by + x;
    if (orow < C && oc < R) out[(size_t)orow * R + oc] = tile[x][ys + i];
  }
}

__global__ void rowsum_dinv(const float* __restrict__ mod, float* __restrict__ dinv, int N) {
  int row = blockIdx.x;
  const float* p = mod + (size_t)row * N;
  float s = 0.f;
  for (int c = threadIdx.x * 4; c < N; c += 1024) {
    float4 v = *(const float4*)(p + c);
    s += (v.x + v.y) + (v.z + v.w);
  }
#pragma unroll
  for (int off = 32; off > 0; off >>= 1) s += __shfl_xor(s, off);
  __shared__ float wsum[4];
  if ((threadIdx.x & 63) == 0) wsum[threadIdx.x >> 6] = s;
  __syncthreads();
  if (threadIdx.x == 0) {
    float t = wsum[0] + wsum[1] + wsum[2] + wsum[3];
    dinv[row] = 1.0f / sqrtf(t + 1.0f);   // +1 for the identity diagonal
  }
}

// adjf[i][j] = dinv_i*(mod[i][j] + (i==j))*dinv_j, in place. N = 8192.
__global__ void normalize_adj(float* __restrict__ mod, const float* __restrict__ dinv) {
  const size_t total = ((size_t)8192 * 8192) >> 2;
  for (size_t i = (size_t)blockIdx.x * blockDim.x + threadIdx.x; i < total;
       i += (size_t)gridDim.x * blockDim.x) {
    size_t e  = i << 2;
    int row   = (int)(e >> 13);
    int col   = (int)(e & 8191);
    float4 v  = *(float4*)(mod + e);
    float di  = dinv[row];
    float4 dj = *(const float4*)(dinv + col);
    v.x *= di * dj.x; v.y *= di * dj.y; v.z *= di * dj.z; v.w *= di * dj.w;
    int d = row - col;
    if (d >= 0 && d < 4) {
      float dd = di * di;
      if (d == 0) v.x += dd; else if (d == 1) v.y += dd;
      else if (d == 2) v.z += dd; else v.w += dd;
    }
    *(float4*)(mod + e) = v;
  }
}

// one wave per row of h2[8192][40]
__global__ void logsoftmax40(const float* __restrict__ h2, float* __restrict__ out) {
  int row  = blockIdx.x * 4 + (threadIdx.x >> 6);
  int lane = threadIdx.x & 63;
  const float* p = h2 + (size_t)row * 40;
  float x = (lane < 40) ? p[lane] : -INFINITY;
  float m = x;
#pragma unroll
  for (int off = 32; off > 0; off >>= 1) m = fmaxf(m, __shfl_xor(m, off));
  float e = (lane < 40) ? expf(x - m) : 0.f;
  float s = e;
#pragma unroll
  for (int off = 32; off > 0; off >>= 1) s += __shfl_xor(s, off);
  if (lane < 40) out[(size_t)row * 40 + lane] = x - m - logf(s);
}

extern "C" void kernel_launch(void* const* d_in, const int* in_sizes, int n_in,
                              void* d_out, int out_size, void* d_ws, size_t ws_size,
                              hipStream_t stream) {
  const float* x   = (const float*)d_in[0];
  const float* adj = (const float*)d_in[1];
  const float* sw  = (const float*)d_in[2];
  const float* sb  = (const float*)d_in[3];
  const float* W0  = (const float*)d_in[4];
  const float* b0  = (const float*)d_in[5];
  const float* W1  = (const float*)d_in[6];
  const float* b1  = (const float*)d_in[7];
  const float* W2  = (const float*)d_in[8];
  const float* b2  = (const float*)d_in[9];
  float* out = (float*)d_out;

  char* ws    = (char*)d_ws;
  float* swT  = (float*)(ws + OFF_SWT);
  float* mod  = (float*)(ws + OFF_MOD);
  float* xwT  = (float*)(ws + OFF_XWT);
  float* h    = (float*)(ws + OFF_H);
  float* h2   = (float*)(ws + OFF_H2);
  float* dinv = (float*)(ws + OFF_DINV);
  float* W0T  = (float*)(ws + OFF_W0T);
  float* W1T  = (float*)(ws + OFF_W1T);
  float* W2T  = (float*)(ws + OFF_W2T);

  dim3 tb(64, 4);
  transpose_f32<<<dim3(128, 128), tb, 0, stream>>>(sw, swT, 8192, 8192);
  transpose_f32<<<dim3(4, 8),  tb, 0, stream>>>(W0, W0T, 512, 256);
  transpose_f32<<<dim3(4, 4),  tb, 0, stream>>>(W1, W1T, 256, 256);
  transpose_f32<<<dim3(1, 4),  tb, 0, stream>>>(W2, W2T, 256, 40);

  // G1: mod = relu(adj @ sw + sb)   [8192 x 8192], the 1.1 TFLOP kernel
  gemm_split<128, 128, 1, true, true><<<4096, 256, 0, stream>>>(
      adj, swT, sb, mod, 8192, 8192, 8192);

  rowsum_dinv<<<8192, 256, 0, stream>>>(mod, dinv, 8192);
  normalize_adj<<<2048, 256, 0, stream>>>(mod, dinv);

  // G2: xwT = (x@W0)^T  via  C[j][i] = sum_k W0T[j][k]*x[i][k]
  gemm_split<128, 64, 0, false, false><<<256, 256, 0, stream>>>(
      W0T, x, nullptr, xwT, 256, 8192, 512);
  // G3: h0 = relu(adjf @ (x@W0) + b0)
  gemm_split<128, 64, 0, true, true><<<256, 256, 0, stream>>>(
      mod, xwT, b0, h, 8192, 256, 8192);
  // G4: xw1T = (h0@W1)^T
  gemm_split<128, 64, 0, false, false><<<256, 256, 0, stream>>>(
      W1T, h, nullptr, xwT, 256, 8192, 256);
  // G5: h1 = relu(adjf @ (h0@W1) + b1)
  gemm_split<128, 64, 0, true, true><<<256, 256, 0, stream>>>(
      mod, xwT, b1, h, 8192, 256, 8192);
  // G6: xw2T = (h1@W2)^T   (M=40, guarded)
  gemm_split<64, 64, 0, false, false><<<128, 256, 0, stream>>>(
      W2T, h, nullptr, xwT, 40, 8192, 256);
  // G7: h2 = adjf @ (h1@W2) + b2   (N=40, guarded)
  gemm_split<128, 64, 0, false, true><<<64, 256, 0, stream>>>(
      mod, xwT, b2, h2, 8192, 40, 8192);

  logsoftmax40<<<2048, 256, 0, stream>>>(h2, out);
}

// Round 2
// 4360.373 us; speedup vs baseline: 2.0972x; 2.0972x over previous
//
#include <hip/hip_runtime.h>
#include <stdint.h>

// ---------------------------------------------------------------------------
// GCN forward, round 2.
// Key change vs round 1: split-bf16 (hi/lo) conversion is hoisted OUT of the
// GEMM into one-shot plane-conversion kernels; the big GEMMs become pure
// bf16-plane kernels using global_load_lds(16B) staging, counted vmcnt(N)
// (never drained in-loop), raw s_barrier, setprio around the MFMA cluster,
// XOR chunk swizzle for conflict-free ds_read_b128, XCD-bijective block swizzle.
// G1 (8192^3) runs as two K=4096 halves so staging planes (256MB) + mod (256MB)
// stay within the round-1-proven ~537MB workspace.
// ---------------------------------------------------------------------------

typedef __attribute__((ext_vector_type(8))) short short8;   // 8 bf16 = 4 VGPR
typedef __attribute__((ext_vector_type(4))) float f32x4;
typedef unsigned short u16;

// ---------------- workspace layout (bytes) ---------------------------------
#define WS_AH   ((size_t)0)            // 64MB  G1 staging A-hi (half-K planes)
#define WS_AL   ((size_t)67108864)     // 64MB  A-lo
#define WS_BH   ((size_t)134217728)    // 64MB  B-hi
#define WS_BL   ((size_t)201326592)    // 64MB  B-lo
#define WS_AFH  ((size_t)0)            // 128MB adjf-hi (reuses staging region)
#define WS_AFL  ((size_t)134217728)    // 128MB adjf-lo
#define WS_MOD  ((size_t)268435456)    // 256MB mod fp32
// after normalize_split consumes mod, its region is recycled:
#define WS_XWT  (WS_MOD + 0)           // 8MB  xw fp32 [256][8192]
#define WS_XPH  (WS_MOD + 8388608)     // 4MB  xw hi plane
#define WS_XPL  (WS_MOD + 12582912)    // 4MB  xw lo plane
#define WS_H    (WS_MOD + 16777216)    // 8MB  h [8192][256] fp32
#define WS_H2   (WS_MOD + 25165824)    // 1.3MB h2 [8192][40]
#define WS_TAIL ((size_t)536870912)
#define WS_DINV (WS_TAIL)              // 32KB
#define WS_W0T  (WS_TAIL + 32768)
#define WS_W1T  (WS_W0T + 524288)
#define WS_W2T  (WS_W1T + 262144)      // ends ~512.9MB

// ---------------- helpers --------------------------------------------------

// fp32 -> (bf16 hi RNE, bf16 lo trunc), two values packed per u32 (LE order).
__device__ __forceinline__ void split2(float x0, float x1, uint32_t& hi, uint32_t& lo) {
  uint32_t u0 = __float_as_uint(x0), u1 = __float_as_uint(x1);
  uint32_t r0 = (u0 + 0x7fffu + ((u0 >> 16) & 1u)) & 0xffff0000u;
  uint32_t r1 = (u1 + 0x7fffu + ((u1 >> 16) & 1u)) & 0xffff0000u;
  float f0 = x0 - __uint_as_float(r0);
  float f1 = x1 - __uint_as_float(r1);
  hi = (r0 >> 16) | r1;
  lo = (__float_as_uint(f0) >> 16) | (__float_as_uint(f1) & 0xffff0000u);
}

__device__ __forceinline__ void glds16(const void* g, void* l) {
  __builtin_amdgcn_global_load_lds(
      (const __attribute__((address_space(1))) void*)g,
      (__attribute__((address_space(3))) void*)l, 16, 0, 0);
}

__device__ __forceinline__ void barrier_raw() {
  asm volatile("" ::: "memory");
  __builtin_amdgcn_s_barrier();
  asm volatile("" ::: "memory");
}

template<int N> __device__ __forceinline__ void waitvcnt() {
  if constexpr (N >= 8)      asm volatile("s_waitcnt vmcnt(8)" ::: "memory");
  else if constexpr (N == 6) asm volatile("s_waitcnt vmcnt(6)" ::: "memory");
  else                       asm volatile("s_waitcnt vmcnt(0)" ::: "memory");
}

// chunk swizzle: row r, k-chunk kc -> slot kc ^ t3(r). Gives 2-way (free)
// bank pattern for ds_read_b128 column reads of a [row][32bf16] tile.
__device__ __forceinline__ int t3(int r) { return (r ^ (r >> 2)) & 3; }

// ---------------- main bf16-plane GEMM -------------------------------------
// C[m][n] (+)= act( sum_k (AH+AL)[m][k] * (BH+BL)[n][k] + bias[n] )
// A planes: [M][K] bf16 (row-major, K-contig).  B planes: [N][K].
// 3-product split accumulation (HH + HL + LH), fp32 acc -> ~fp32 accuracy.
// BK=32. LDS buffer = [A-hi][A-lo][B-hi][B-lo], each [rows][4 swizzled 16B chunks].
template<int BM, int BN, int WR, int WC, int MAP, bool LOADC, bool RELU, bool BIAS>
__global__ __launch_bounds__(WR * WC * 64, 2)
void gemm3(const u16* __restrict__ AH, const u16* __restrict__ AL,
           const u16* __restrict__ BH, const u16* __restrict__ BL,
           const float* __restrict__ bias, float* __restrict__ C,
           int M, int N, int K, int nbn) {
  constexpr int NW   = WR * WC;
  constexpr int WM   = BM / WR, WN = BN / WC;
  constexpr int MF   = WM / 16, NF = WN / 16;
  constexpr int APL  = BM * 64;            // bytes per A plane (32 bf16/row)
  constexpr int BPL  = BN * 64;
  constexpr int ABUF = 2 * APL;
  constexpr int SZB  = ABUF + 2 * BPL;     // one K-step buffer
  constexpr int LPA  = BM / 16 / NW;       // wave-loads per A plane per wave
  constexpr int LPB  = BN / 16 / NW;
  constexpr int NLD  = 2 * (LPA + LPB);    // gload_lds per wave per K-step

  __shared__ char sm[2 * SZB];

  const int tid  = threadIdx.x;
  const int lane = tid & 63;
  const int wid  = tid >> 6;
  const int l16  = lane & 15;
  const int kq   = lane >> 4;

  // XCD-bijective swizzle (nwg % 8 == 0 at every call site)
  const int nwg = gridDim.x;
  const int bid = blockIdx.x;
  const int swz = (bid & 7) * (nwg >> 3) + (bid >> 3);
  int bm_i, bn_i;
  if (MAP == 1) {  // 8 row-tiles share each B panel (L2/L3 locality for G1)
    const int per = 8 * nbn;
    const int g = swz / per, r = swz % per;
    bm_i = g * 8 + (r & 7);
    bn_i = r >> 3;
  } else {
    bm_i = swz / nbn;
    bn_i = swz % nbn;
  }
  const int bm = bm_i * BM, bn = bn_i * BN;

  // staging: one gload_lds covers 16 rows x 4 chunks (64 lanes x 16B = 1KB).
  // LDS dest is linear; the chunk swizzle is applied on the GLOBAL source addr.
  size_t aoffg[LPA]; int aoffl[LPA];
#pragma unroll
  for (int j = 0; j < LPA; ++j) {
    const int row0 = (wid * LPA + j) * 16;
    const int row  = row0 + (lane >> 2);
    const int kc   = (lane & 3) ^ t3(row);
    aoffg[j] = (size_t)(bm + row) * K + kc * 8;
    aoffl[j] = row0 * 64;
  }
  size_t boffg[LPB]; int boffl[LPB];
#pragma unroll
  for (int j = 0; j < LPB; ++j) {
    const int row0 = (wid * LPB + j) * 16;
    const int row  = row0 + (lane >> 2);
    const int kc   = (lane & 3) ^ t3(row);
    boffg[j] = (size_t)(bn + row) * K + kc * 8;
    boffl[j] = row0 * 64;
  }

  // fragment read offsets (consistent with the same swizzle)
  const int wr = wid / WC, wc = wid % WC;
  int offA[MF], offB[NF];
#pragma unroll
  for (int m = 0; m < MF; ++m) {
    const int row = wr * WM + m * 16 + l16;
    offA[m] = row * 64 + ((kq ^ t3(row)) << 4);
  }
#pragma unroll
  for (int n = 0; n < NF; ++n) {
    const int row = wc * WN + n * 16 + l16;
    offB[n] = row * 64 + ((kq ^ t3(row)) << 4);
  }

  f32x4 acc[MF][NF] = {};
  const int NT = K >> 5;   // K % 32 == 0, NT >= 2 at all call sites

  auto STAGE = [&](int bb, int kt) {
    const int ke = kt * 32;
#pragma unroll
    for (int j = 0; j < LPA; ++j) {
      glds16(AH + aoffg[j] + ke, sm + bb + aoffl[j]);
      glds16(AL + aoffg[j] + ke, sm + bb + APL + aoffl[j]);
    }
#pragma unroll
    for (int j = 0; j < LPB; ++j) {
      glds16(BH + boffg[j] + ke, sm + bb + ABUF + boffl[j]);
      glds16(BL + boffg[j] + ke, sm + bb + ABUF + BPL + boffl[j]);
    }
  };

  STAGE(0, 0);
  STAGE(SZB, 1);
  waitvcnt<NLD>();           // buf0 ready; buf1 loads stay in flight
  barrier_raw();

  int bb = 0;
  for (int kt = 0; kt < NT; ++kt) {
    short8 bh[NF], blo[NF];
#pragma unroll
    for (int n = 0; n < NF; ++n) {
      bh[n]  = *(const short8*)(sm + bb + ABUF + offB[n]);
      blo[n] = *(const short8*)(sm + bb + ABUF + BPL + offB[n]);
    }
    __builtin_amdgcn_s_setprio(1);
#pragma unroll
    for (int m = 0; m < MF; ++m) {
      const short8 ah = *(const short8*)(sm + bb + offA[m]);
      const short8 al = *(const short8*)(sm + bb + APL + offA[m]);
#pragma unroll
      for (int n = 0; n < NF; ++n) {
        acc[m][n] = __builtin_amdgcn_mfma_f32_16x16x32_bf16(ah, bh[n],  acc[m][n], 0, 0, 0);
        acc[m][n] = __builtin_amdgcn_mfma_f32_16x16x32_bf16(ah, blo[n], acc[m][n], 0, 0, 0);
        acc[m][n] = __builtin_amdgcn_mfma_f32_16x16x32_bf16(al, bh[n],  acc[m][n], 0, 0, 0);
      }
    }
    __builtin_amdgcn_s_setprio(0);
    barrier_raw();                     // all waves done reading bb
    if (kt + 2 < NT) {
      STAGE(bb, kt + 2);               // overwrite bb with tile kt+2
      waitvcnt<NLD>();                 // tile kt+1 (other buffer) now complete
    } else {
      waitvcnt<0>();                   // tail: drain
    }
    barrier_raw();
    bb ^= SZB;
  }

  // epilogue: C/D layout col=lane&15, row=(lane>>4)*4+r (verified round 1)
#pragma unroll
  for (int n = 0; n < NF; ++n) {
    const int gn = bn + wc * WN + n * 16 + l16;
    float bv = 0.f;
    if (BIAS && gn < N) bv = bias[gn];
#pragma unroll
    for (int m = 0; m < MF; ++m) {
      const int gm = bm + wr * WM + m * 16 + kq * 4;
#pragma unroll
      for (int r = 0; r < 4; ++r) {
        if (gn < N) {
          const size_t idx = (size_t)(gm + r) * N + gn;
          float v = acc[m][n][r] + bv;
          if (LOADC) v += C[idx];
          if (RELU) v = fmaxf(v, 0.f);
          C[idx] = v;
        }
      }
    }
  }
}

// ---------------- conversion kernels ---------------------------------------

// src fp32 [R][srcStride], cols c0..c0+C -> dh/dl bf16 planes [RP][C] (C=2^lc2).
// rows >= R write zeros (padding).
__global__ void split_plane(const float* __restrict__ src, u16* __restrict__ dh,
                            u16* __restrict__ dl, int R, int RP, int lc2,
                            int srcStride, int c0) {
  const int Cm1 = (1 << lc2) - 1;
  const size_t total = ((size_t)RP << lc2) >> 2;
  for (size_t i = (size_t)blockIdx.x * blockDim.x + threadIdx.x; i < total;
       i += (size_t)gridDim.x * blockDim.x) {
    const size_t e = i << 2;
    const int r = (int)(e >> lc2);
    const int c = (int)(e & Cm1);
    float4 v = make_float4(0.f, 0.f, 0.f, 0.f);
    if (r < R) v = *(const float4*)(src + (size_t)r * srcStride + c0 + c);
    uint32_t h0, l0, h1, l1;
    split2(v.x, v.y, h0, l0);
    split2(v.z, v.w, h1, l1);
    *(uint2*)(dh + e) = make_uint2(h0, h1);
    *(uint2*)(dl + e) = make_uint2(l0, l1);
  }
}

// sw [8192][8192] fp32 -> transposed half-K planes dh/dl [8192][KH]:
// dh[n][c] = hi(sw[k0+c][n]).
__global__ void transpose_split(const float* __restrict__ sw, u16* __restrict__ dh,
                                u16* __restrict__ dl, int k0, int KH) {
  __shared__ float t[64][65];
  const int n0 = blockIdx.x << 6;
  const int c0 = blockIdx.y << 6;
  const int tid = threadIdx.x;               // 256
  const int tx = tid & 63, ty = tid >> 6;
#pragma unroll
  for (int i = 0; i < 64; i += 4)
    t[ty + i][tx] = sw[(size_t)(k0 + c0 + ty + i) * 8192 + n0 + tx];
  __syncthreads();
  const int nl = tid >> 2;
  const int cb = (tid & 3) << 4;
  u16* ph = dh + (size_t)(n0 + nl) * KH + c0 + cb;
  u16* pl = dl + (size_t)(n0 + nl) * KH + c0 + cb;
#pragma unroll
  for (int j = 0; j < 16; j += 2) {
    uint32_t h, l;
    split2(t[cb + j][nl], t[cb + j + 1][nl], h, l);
    *(uint32_t*)(ph + j) = h;
    *(uint32_t*)(pl + j) = l;
  }
}

// mod fp32 + dinv -> adjf hi/lo planes:  v = (mod[i][j] + (i==j)) * di * dj
__global__ void normalize_split(const float* __restrict__ mod, const float* __restrict__ dinv,
                                u16* __restrict__ dh, u16* __restrict__ dl) {
  const size_t total = ((size_t)8192 * 8192) >> 2;
  for (size_t i = (size_t)blockIdx.x * blockDim.x + threadIdx.x; i < total;
       i += (size_t)gridDim.x * blockDim.x) {
    const size_t e = i << 2;
    const int row = (int)(e >> 13);
    const int col = (int)(e & 8191);
    float4 v = *(const float4*)(mod + e);
    const int d = row - col;
    if (d >= 0 && d < 4) {
      if (d == 0) v.x += 1.f; else if (d == 1) v.y += 1.f;
      else if (d == 2) v.z += 1.f; else v.w += 1.f;
    }
    const float di = dinv[row];
    const float4 dj = *(const float4*)(dinv + col);
    v.x *= di * dj.x; v.y *= di * dj.y; v.z *= di * dj.z; v.w *= di * dj.w;
    uint32_t h0, l0, h1, l1;
    split2(v.x, v.y, h0, l0);
    split2(v.z, v.w, h1, l1);
    *(uint2*)(dh + e) = make_uint2(h0, h1);
    *(uint2*)(dl + e) = make_uint2(l0, l1);
  }
}

// ---------------- small-GEMM path (round-1 kernel, validated) --------------

__device__ __forceinline__ int lds_off(int row, int hl, int k) {
  int chunk = (hl << 2) | (k >> 3);
  return (row << 7) + ((chunk ^ (row & 7)) << 4) + ((k & 7) << 1);
}

template<int BM, int BN, int MAP, bool RELU, bool BIAS>
__global__ __launch_bounds__(256, 2)
void gemm_split(const float* __restrict__ A, const float* __restrict__ Bt,
                const float* __restrict__ bias, float* __restrict__ C,
                int M, int N, int K) {
  constexpr int WM = BM / 2, WN = BN / 2;
  constexpr int MF = WM / 16, NF = WN / 16;
  constexpr int PA = BM / 32, PB = BN / 32;
  __shared__ char smem[(BM + BN) * 128];
  char* smA = smem;
  char* smB = smem + BM * 128;

  const int tid  = threadIdx.x;
  const int lane = tid & 63;
  const int wid  = tid >> 6;
  const int l16  = lane & 15;
  const int lk8  = (lane >> 4) << 3;

  const int nbn = (N + BN - 1) / BN;
  int bm_i = blockIdx.x / nbn, bn_i = blockIdx.x % nbn;
  const int bm = bm_i * BM, bn = bn_i * BN;

  const int tr = tid >> 3;
  const int tc = (tid & 7) << 2;

  const float* aptr[PA]; bool aok[PA]; int aoff[PA];
#pragma unroll
  for (int p = 0; p < PA; ++p) {
    int row = p * 32 + tr, gr = bm + row;
    aok[p] = gr < M;
    aptr[p] = A + (size_t)gr * K + tc;
    aoff[p] = lds_off(row, 0, tc);
  }
  const float* bptr[PB]; bool bok[PB]; int boff[PB];
#pragma unroll
  for (int p = 0; p < PB; ++p) {
    int row = p * 32 + tr, gc = bn + row;
    bok[p] = gc < N;
    bptr[p] = Bt + (size_t)gc * K + tc;
    boff[p] = lds_off(row, 0, tc);
  }

  int offFA[MF], offFB[NF];
#pragma unroll
  for (int m = 0; m < MF; ++m)
    offFA[m] = lds_off((wid >> 1) * WM + m * 16 + l16, 0, lk8);
#pragma unroll
  for (int n = 0; n < NF; ++n)
    offFB[n] = lds_off((wid & 1) * WN + n * 16 + l16, 0, lk8);

  f32x4 acc[MF][NF] = {};
  const int NT = K >> 5;

  float4 cA[PA], cB[PB], nA[PA], nB[PB];

  auto LOADT = [&](float4* va, float4* vb, int kt) {
    const size_t ko = (size_t)kt << 5;
#pragma unroll
    for (int p = 0; p < PA; ++p) {
      float4 v = make_float4(0.f, 0.f, 0.f, 0.f);
      if (aok[p]) v = *(const float4*)(aptr[p] + ko);
      va[p] = v;
    }
#pragma unroll
    for (int p = 0; p < PB; ++p) {
      float4 v = make_float4(0.f, 0.f, 0.f, 0.f);
      if (bok[p]) v = *(const float4*)(bptr[p] + ko);
      vb[p] = v;
    }
  };

  auto STAGE = [&](const float4* va, const float4* vb) {
#pragma unroll
    for (int p = 0; p < PA; ++p) {
      uint32_t h0, l0, h1, l1;
      split2(va[p].x, va[p].y, h0, l0);
      split2(va[p].z, va[p].w, h1, l1);
      *(uint2*)(smA + aoff[p])        = make_uint2(h0, h1);
      *(uint2*)(smA + (aoff[p] ^ 64)) = make_uint2(l0, l1);
    }
#pragma unroll
    for (int p = 0; p < PB; ++p) {
      uint32_t h0, l0, h1, l1;
      split2(vb[p].x, vb[p].y, h0, l0);
      split2(vb[p].z, vb[p].w, h1, l1);
      *(uint2*)(smB + boff[p])        = make_uint2(h0, h1);
      *(uint2*)(smB + (boff[p] ^ 64)) = make_uint2(l0, l1);
    }
  };

  auto COMPUTE = [&]() {
    short8 aH[MF], aL[MF];
#pragma unroll
    for (int m = 0; m < MF; ++m) {
      aH[m] = *(const short8*)(smA + offFA[m]);
      aL[m] = *(const short8*)(smA + (offFA[m] ^ 64));
    }
#pragma unroll
    for (int n = 0; n < NF; ++n) {
      short8 bH = *(const short8*)(smB + offFB[n]);
      short8 bL = *(const short8*)(smB + (offFB[n] ^ 64));
#pragma unroll
      for (int m = 0; m < MF; ++m) {
        acc[m][n] = __builtin_amdgcn_mfma_f32_16x16x32_bf16(aH[m], bH, acc[m][n], 0, 0, 0);
        acc[m][n] = __builtin_amdgcn_mfma_f32_16x16x32_bf16(aH[m], bL, acc[m][n], 0, 0, 0);
        acc[m][n] = __builtin_amdgcn_mfma_f32_16x16x32_bf16(aL[m], bH, acc[m][n], 0, 0, 0);
      }
    }
  };

  LOADT(cA, cB, 0);
  for (int kt = 0; kt < NT; kt += 2) {
    STAGE(cA, cB);
    __syncthreads();
    LOADT(nA, nB, kt + 1);
    COMPUTE();
    __syncthreads();
    STAGE(nA, nB);
    __syncthreads();
    if (kt + 2 < NT) LOADT(cA, cB, kt + 2);
    COMPUTE();
    __syncthreads();
  }

  const int wm = (wid >> 1) * WM, wn = (wid & 1) * WN;
#pragma unroll
  for (int n = 0; n < NF; ++n) {
    int gn = bn + wn + n * 16 + l16;
    float bv = 0.f;
    if (BIAS && gn < N) bv = bias[gn];
#pragma unroll
    for (int m = 0; m < MF; ++m) {
      int gm0 = bm + wm + m * 16 + ((lane >> 4) << 2);
#pragma unroll
      for (int r = 0; r < 4; ++r) {
        int gm = gm0 + r;
        if (gm < M && gn < N) {
          float v = acc[m][n][r] + bv;
          if (RELU) v = fmaxf(v, 0.f);
          C[(size_t)gm * N + gn] = v;
        }
      }
    }
  }
}

// ---------------- misc kernels (round-1, validated) ------------------------

__global__ void transpose_f32(const float* __restrict__ in, float* __restrict__ out,
                              int R, int C) {
  __shared__ float tile[64][65];
  int bx = blockIdx.x << 6;
  int by = blockIdx.y << 6;
  int x = threadIdx.x;
  int ys = threadIdx.y;
#pragma unroll
  for (int i = 0; i < 64; i += 4) {
    int r = by + ys + i, c = bx + x;
    float v = 0.f;
    if (r < R && c < C) v = in[(size_t)r * C + c];
    tile[ys + i][x] = v;
  }
  __syncthreads();
#pragma unroll
  for (int i = 0; i < 64; i += 4) {
    int orow = bx + ys + i, oc = by + x;
    if (orow < C && oc < R) out[(size_t)orow * R + oc] = tile[x][ys + i];
  }
}

__global__ void rowsum_dinv(const float* __restrict__ mod, float* __restrict__ dinv, int N) {
  int row = blockIdx.x;
  const float* p = mod + (size_t)row * N;
  float s = 0.f;
  for (int c = threadIdx.x * 4; c < N; c += 1024) {
    float4 v = *(const float4*)(p + c);
    s += (v.x + v.y) + (v.z + v.w);
  }
#pragma unroll
  for (int off = 32; off > 0; off >>= 1) s += __shfl_xor(s, off);
  __shared__ float wsum[4];
  if ((threadIdx.x & 63) == 0) wsum[threadIdx.x >> 6] = s;
  __syncthreads();
  if (threadIdx.x == 0) {
    float t = wsum[0] + wsum[1] + wsum[2] + wsum[3];
    dinv[row] = 1.0f / sqrtf(t + 1.0f);   // +1 for identity diagonal
  }
}

__global__ void logsoftmax40(const float* __restrict__ h2, float* __restrict__ out) {
  int row = blockIdx.x * 4 + (threadIdx.x >> 6);
  int lane = threadIdx.x & 63;
  const float* p = h2 + (size_t)row * 40;
  float x = (lane < 40) ? p[lane] : -INFINITY;
  float m = x;
#pragma unroll
  for (int off = 32; off > 0; off >>= 1) m = fmaxf(m, __shfl_xor(m, off));
  float e = (lane < 40) ? expf(x - m) : 0.f;
  float s = e;
#pragma unroll
  for (int off = 32; off > 0; off >>= 1) s += __shfl_xor(s, off);
  if (lane < 40) out[(size_t)row * 40 + lane] = x - m - logf(s);
}

// ---------------- launcher -------------------------------------------------

extern "C" void kernel_launch(void* const* d_in, const int* in_sizes, int n_in,
                              void* d_out, int out_size, void* d_ws, size_t ws_size,
                              hipStream_t stream) {
  const float* x   = (const float*)d_in[0];
  const float* adj = (const float*)d_in[1];
  const float* sw  = (const float*)d_in[2];
  const float* sb  = (const float*)d_in[3];
  const float* W0  = (const float*)d_in[4];
  const float* b0  = (const float*)d_in[5];
  const float* W1  = (const float*)d_in[6];
  const float* b1  = (const float*)d_in[7];
  const float* W2  = (const float*)d_in[8];
  const float* b2  = (const float*)d_in[9];
  float* out = (float*)d_out;

  char* ws = (char*)d_ws;
  u16* AH = (u16*)(ws + WS_AH);
  u16* AL = (u16*)(ws + WS_AL);
  u16* BH = (u16*)(ws + WS_BH);
  u16* BL = (u16*)(ws + WS_BL);
  u16* afH = (u16*)(ws + WS_AFH);
  u16* afL = (u16*)(ws + WS_AFL);
  float* mod  = (float*)(ws + WS_MOD);
  float* xwT  = (float*)(ws + WS_XWT);
  u16* xpH    = (u16*)(ws + WS_XPH);
  u16* xpL    = (u16*)(ws + WS_XPL);
  float* h    = (float*)(ws + WS_H);
  float* h2   = (float*)(ws + WS_H2);
  float* dinv = (float*)(ws + WS_DINV);
  float* W0T  = (float*)(ws + WS_W0T);
  float* W1T  = (float*)(ws + WS_W1T);
  float* W2T  = (float*)(ws + WS_W2T);

  dim3 tb(64, 4);
  transpose_f32<<<dim3(4, 8), tb, 0, stream>>>(W0, W0T, 512, 256);
  transpose_f32<<<dim3(4, 4), tb, 0, stream>>>(W1, W1T, 256, 256);
  transpose_f32<<<dim3(1, 4), tb, 0, stream>>>(W2, W2T, 256, 40);

  // ---- G1: mod = relu(adj @ sw + sb), two K=4096 halves ----
  // pass 0
  split_plane<<<2048, 256, 0, stream>>>(adj, AH, AL, 8192, 8192, 12, 8192, 0);
  transpose_split<<<dim3(128, 64), 256, 0, stream>>>(sw, BH, BL, 0, 4096);
  gemm3<256, 256, 2, 4, 1, false, false, false><<<1024, 512, 0, stream>>>(
      AH, AL, BH, BL, nullptr, mod, 8192, 8192, 4096, 32);
  // pass 1 (accumulate + bias + relu)
  split_plane<<<2048, 256, 0, stream>>>(adj, AH, AL, 8192, 8192, 12, 8192, 4096);
  transpose_split<<<dim3(128, 64), 256, 0, stream>>>(sw, BH, BL, 4096, 4096);
  gemm3<256, 256, 2, 4, 1, true, true, true><<<1024, 512, 0, stream>>>(
      AH, AL, BH, BL, sb, mod, 8192, 8192, 4096, 32);

  // ---- normalization: adjf planes (overwrite staging region) ----
  rowsum_dinv<<<8192, 256, 0, stream>>>(mod, dinv, 8192);
  normalize_split<<<2048, 256, 0, stream>>>(mod, dinv, afH, afL);
  // mod region now free -> recycled for xwT/xpH/xpL/h/h2

  // ---- layer 0 ----
  gemm_split<128, 64, 0, false, false><<<256, 256, 0, stream>>>(
      W0T, x, nullptr, xwT, 256, 8192, 512);                    // xwT = (x@W0)^T
  split_plane<<<512, 256, 0, stream>>>(xwT, xpH, xpL, 256, 256, 13, 8192, 0);
  gemm3<64, 128, 2, 2, 0, false, true, true><<<256, 256, 0, stream>>>(
      afH, afL, xpH, xpL, b0, h, 8192, 256, 8192, 2);           // h0

  // ---- layer 1 ----
  gemm_split<128, 64, 0, false, false><<<256, 256, 0, stream>>>(
      W1T, h, nullptr, xwT, 256, 8192, 256);                    // (h0@W1)^T
  split_plane<<<512, 256, 0, stream>>>(xwT, xpH, xpL, 256, 256, 13, 8192, 0);
  gemm3<64, 128, 2, 2, 0, false, true, true><<<256, 256, 0, stream>>>(
      afH, afL, xpH, xpL, b1, h, 8192, 256, 8192, 2);           // h1

  // ---- layer 2 ----
  gemm_split<64, 64, 0, false, false><<<128, 256, 0, stream>>>(
      W2T, h, nullptr, xwT, 40, 8192, 256);                     // (h1@W2)^T [40][8192]
  split_plane<<<512, 256, 0, stream>>>(xwT, xpH, xpL, 40, 128, 13, 8192, 0);  // pad to 128 rows
  gemm3<64, 128, 2, 2, 0, false, false, true><<<128, 256, 0, stream>>>(
      afH, afL, xpH, xpL, b2, h2, 8192, 40, 8192, 1);           // h2 (N guard)

  logsoftmax40<<<2048, 256, 0, stream>>>(h2, out);
}